// Round 2
// baseline (1166.385 us; speedup 1.0000x reference)
//
#include <hip/hip_runtime.h>
#include <hip/hip_bf16.h>

// CP factorization inner product:
// out[b] = sum_r prod_m factors[m, idx[b,m], r],  ORDER=4, RANK=128.
// Memory-bound gather: 4 random 512B rows per batch element.
// Half-wave (32 lanes) per batch element; lane l covers ranks [4l, 4l+3]
// via float4 -> each wave64 load instruction fetches 2 contiguous 512B rows.

#define ORDER 4
#define MODES_DIM 500000
#define RANK 128

__global__ __launch_bounds__(256) void cp_gather_kernel(
    const int* __restrict__ indices,      // [BATCH, 4]
    const float* __restrict__ factors,    // [4, MODES_DIM, RANK]
    float* __restrict__ out,              // [BATCH]
    int batch) {
    const int gid  = blockIdx.x * blockDim.x + threadIdx.x;
    const int pair = gid >> 6;            // wave id: one wave = 2 batch elems
    const int lane = threadIdx.x & 63;
    const int half = lane >> 5;           // which batch elem in this wave
    const int l    = lane & 31;           // lane within half-wave

    const int b = pair * 2 + half;
    if (b >= batch) return;

    // All 32 lanes of a half broadcast-load the same 16B of indices (L1 hit).
    const int4 iv = reinterpret_cast<const int4*>(indices)[b];

    const size_t MR = (size_t)MODES_DIM * RANK;   // per-mode stride (64M floats)
    const size_t ro = (size_t)l * 4;              // rank offset for this lane

    const float4 a0 = *reinterpret_cast<const float4*>(factors + 0 * MR + (size_t)iv.x * RANK + ro);
    const float4 a1 = *reinterpret_cast<const float4*>(factors + 1 * MR + (size_t)iv.y * RANK + ro);
    const float4 a2 = *reinterpret_cast<const float4*>(factors + 2 * MR + (size_t)iv.z * RANK + ro);
    const float4 a3 = *reinterpret_cast<const float4*>(factors + 3 * MR + (size_t)iv.w * RANK + ro);

    float s = a0.x * a1.x * a2.x * a3.x
            + a0.y * a1.y * a2.y * a3.y
            + a0.z * a1.z * a2.z * a3.z
            + a0.w * a1.w * a2.w * a3.w;

    // Reduce across the 32-lane half. XOR offsets < 32 stay within the half
    // on a 64-lane wave.
    #pragma unroll
    for (int off = 16; off > 0; off >>= 1)
        s += __shfl_xor(s, off, 64);

    if (l == 0) out[b] = s;
}

extern "C" void kernel_launch(void* const* d_in, const int* in_sizes, int n_in,
                              void* d_out, int out_size, void* d_ws, size_t ws_size,
                              hipStream_t stream) {
    const int* indices   = (const int*)d_in[0];     // [BATCH, 4] int32
    const float* factors = (const float*)d_in[1];   // [4, MODES_DIM, RANK] f32
    float* out           = (float*)d_out;           // [BATCH] f32

    const int batch = in_sizes[0] / ORDER;          // 262144
    // 2 batch elems per wave, 4 waves per 256-thread block
    const int elems_per_block = 8;
    const int grid = (batch + elems_per_block - 1) / elems_per_block;
    cp_gather_kernel<<<grid, 256, 0, stream>>>(indices, factors, out, batch);
}